// Round 10
// baseline (122.616 us; speedup 1.0000x reference)
//
#include <hip/hip_runtime.h>
#include <math.h>

// MedianPool 17x17 stride 1, zero-padded SAME. Input (1,4,256,256) fp32.
//
// Round 7 kernel, third resubmit (r7/r8/r9 benches GPUAcquisitionTimeout --
// never ran; preserving the clean A/B vs r6's measurement):
//   straight-line scalarization of the window.
//   r6 post-mortem: asm-pin changed NOTHING (VGPR 28, conflicts bit-identical)
//   => w[37] is a scratch-resident alloca; SROA never promoted it, and every
//   seed/scan/extract pass pays scratch round-trips + loop bookkeeping
//   (measured ~2285 VALU instrs/lane vs ~960 static best-case).
//   Fix: NO array, NO loops over window values -- 37 named scalars via
//   X-macro straight-line code. SSA from birth; nothing for SROA to miss.
//   Algorithm identical to r2 (passed, absmax 0): seed counts -> zero
//   shortcut; density-guided first probe; regula-falsi/bisection hybrid;
//   extract 2 smallest in final bracket; octet shfl merges.
// Predicted: VGPR >= 60 (gate), dur 79.5 -> 38-52 us, VALUBusy 75-85%.

#define RAD 8
#define TW 8
#define TH 4
#define PW (TW + 2 * RAD)   // 24
#define PH (TH + 2 * RAD)   // 20
#define LDSW 25             // padded LDS stride
#define MEDRANK 144         // 0-based rank of lower median (of 289)

// X-macro over the 37 per-lane window slots
#define XP(OP) OP(0) OP(1) OP(2) OP(3) OP(4) OP(5) OP(6) OP(7) OP(8) OP(9) \
    OP(10) OP(11) OP(12) OP(13) OP(14) OP(15) OP(16) OP(17) OP(18) OP(19) \
    OP(20) OP(21) OP(22) OP(23) OP(24) OP(25) OP(26) OP(27) OP(28) OP(29) \
    OP(30) OP(31) OP(32) OP(33) OP(34) OP(35) OP(36)

__global__ __launch_bounds__(256, 2)
void median17_kernel(const float* __restrict__ x, float* __restrict__ out) {
    __shared__ float tile[PH * LDSW];

    const int tid = threadIdx.x;
    const int bid = blockIdx.x;
    // grid: 4 ch * 64 y-tiles * 32 x-tiles = 8192 blocks, 32 pixels/block
    const int c  = bid >> 11;
    const int t  = bid & 2047;
    const int oy = (t >> 5) * TH;
    const int ox = (t & 31) * TW;
    const float* xc = x + c * 65536;

    // stage 20x24 patch, zero padded
    for (int i = tid; i < PH * PW; i += 256) {
        int r   = i / PW;
        int col = i - r * PW;
        int gy  = oy - RAD + r;
        int gx  = ox - RAD + col;
        float v = 0.0f;
        if ((unsigned)gy < 256u && (unsigned)gx < 256u) v = xc[gy * 256 + gx];
        tile[r * LDSW + col] = v;
    }
    __syncthreads();

    const int j  = tid & 7;     // lane within octet (one pixel per 8 lanes)
    const int g  = tid >> 3;    // pixel 0..31
    const int py = g >> 3;
    const int px = g & 7;

    const float FINF = __builtin_inff();

    // lane j owns flat window indices [37j, 37j+37); f>=289 padded +INF.
    // flat f -> (dy,dx) = (f/17, f%17). 37 NAMED scalars, straight-line.
#define DECLW(K) float w##K;
    XP(DECLW)
#undef DECLW
    {
        const int f0   = 37 * j;
        const int dy0  = f0 / 17;
        const bool okj = (j < 7);
        int dx = f0 - dy0 * 17;
        int a  = (py + dy0) * LDSW + px + dx;
#define LOADW(K) {                                                   \
        const bool ok = (K < 30) || okj;   /* f0+K < 289 */          \
        float v  = tile[ok ? a : 0];                                 \
        w##K     = ok ? v : FINF;                                    \
        const bool wr = (dx == 16);                                  \
        a  += wr ? (LDSW - 16) : 1;                                  \
        dx  = wr ? 0 : dx + 1;                                       \
    }
        XP(LOADW)
#undef LOADW
    }

    // seed counters: c0 = #(v<0), cz = #(v==0), packed reduce over octet
    int cn = 0, ce = 0;
#define SEEDW(K) { cn += (w##K < 0.0f) ? 1 : 0; ce += (w##K == 0.0f) ? 1 : 0; }
    XP(SEEDW)
#undef SEEDW
    int pk = cn | (ce << 16);
    pk += __shfl_xor(pk, 1);
    pk += __shfl_xor(pk, 2);
    pk += __shfl_xor(pk, 4);
    const int c0 = pk & 0xffff;
    const int cz = pk >> 16;

    float med;
    if (c0 <= MEDRANK && MEDRANK < c0 + cz) {
        // zero is the exact lower median (border pixels with padding dups)
        med = 0.0f;
    } else {
        float lo, hi; int lc, hc;
        if (c0 > MEDRANK) { lo = -FINF; lc = 0;  hi = 0.0f; hc = c0;  }
        else              { lo = 0.0f;  lc = c0; hi = FINF; hc = 289; }

        for (int it = 0; it < 100; ++it) {
            if (hc - lc <= 2) break;
            float mid;
            if (it == 0) {
                // density-guided secant through (0, c0); sign matches side
                mid = 2.5066283f * (0.5f - (float)c0 * (1.0f / 289.0f));
            } else if (hi == FINF) {            // lo > 0 measured; expand up
                mid = fminf(2.0f * lo, 3.0e38f);
            } else if (lo == -FINF) {           // hi < 0 measured; expand down
                mid = fmaxf(2.0f * hi, -3.0e38f);
            } else if (it & 1) {                // safeguarded bisection
                mid = 0.5f * (lo + hi);
            } else {                            // regula falsi on counts
                float wd   = hi - lo;
                float frac = (float)(144 - lc) + 0.5f;
                mid = lo + wd * (frac / (float)(hc - lc));
                mid = fminf(fmaxf(mid, lo + 0.03125f * wd), hi - 0.03125f * wd);
            }
            if (!(mid > lo && mid < hi)) break;   // degenerate bracket

            int q = 0;
#define CNTW(K) { q += (w##K < mid) ? 1 : 0; }
            XP(CNTW)
#undef CNTW
            q += __shfl_xor(q, 1);
            q += __shfl_xor(q, 2);
            q += __shfl_xor(q, 4);

            if (q <= MEDRANK) { lo = mid; lc = q; }
            else              { hi = mid; hc = q; }
        }

        // extract rank rk (0 or 1) among values in [lo, hi).
        // degenerate-break case: only one representable value in [lo,hi),
        // so s0 == s1 and either pick is exact.
        const int rk = MEDRANK - lc;
        float q0a = FINF, q1a = FINF, q0b = FINF, q1b = FINF;
#define EXTW(K) {                                                    \
        float v  = w##K;                                             \
        bool  in = (v >= lo) & (v < hi);                             \
        float xv = in ? v : FINF;                                    \
        if ((K & 1) == 0) {                                          \
            float t0 = fminf(q0a, xv);                               \
            q1a = fminf(q1a, fmaxf(q0a, xv));                        \
            q0a = t0;                                                \
        } else {                                                     \
            float t0 = fminf(q0b, xv);                               \
            q1b = fminf(q1b, fmaxf(q0b, xv));                        \
            q0b = t0;                                                \
        }                                                            \
    }
        XP(EXTW)
#undef EXTW
        float s0 = fminf(q0a, q0b);
        float s1 = fminf(fminf(q1a, q1b), fmaxf(q0a, q0b));
#pragma unroll
        for (int d = 1; d <= 4; d <<= 1) {
            float r0 = __shfl_xor(s0, d);
            float r1 = __shfl_xor(s1, d);
            float n0 = fminf(s0, r0);
            float n1 = fminf(fminf(s1, r1), fmaxf(s0, r0));
            s0 = n0; s1 = n1;
        }
        med = (rk == 0) ? s0 : s1;
    }

    if (j == 0) {
        out[c * 65536 + (oy + py) * 256 + ox + px] = med;
    }
}

extern "C" void kernel_launch(void* const* d_in, const int* in_sizes, int n_in,
                              void* d_out, int out_size, void* d_ws, size_t ws_size,
                              hipStream_t stream) {
    const float* x = (const float*)d_in[0];
    float* out = (float*)d_out;
    median17_kernel<<<dim3(8192), dim3(256), 0, stream>>>(x, out);
}